// Round 2
// baseline (268.929 us; speedup 1.0000x reference)
//
#include <hip/hip_runtime.h>
#include <math.h>

#define DD 2048
#define EE 64
#define TM 64            // tokens per block
#define BK 64            // k per chunk
#define NCHUNK (DD / BK) // 32
#define THREADS 256
#define LSTR (EE + 1)    // logits stride 65: bank = (t + e) % 32 -> 2-way, free

// Tile layout in LDS (forced by global_load_lds: wave-uniform base + lane*16):
// row-major [row][64 k floats], physical quad q holds logical quad (q ^ (row&7)).
__global__ __launch_bounds__(THREADS) void router_kernel(
    const float* __restrict__ x, const float* __restrict__ W,
    const float* __restrict__ bias_g, float* __restrict__ out, int n_tokens)
{
    __shared__ float xs[2][TM * BK];
    __shared__ float ws[2][EE * BK];
    __shared__ float logits[TM * LSTR];

    const int tid   = threadIdx.x;
    const int lane  = tid & 63;
    const int wv_id = tid >> 6;   // wave 0..3
    const int tx    = tid & 15;   // experts {tx+16j}
    const int ty    = tid >> 4;   // tokens  {ty+16i}  (ty 0..15)
    const int tBase = blockIdx.x * TM;

    const int rg = lane >> 4;     // row-in-group 0..3 for staging
    const int p  = lane & 15;     // physical quad for staging

    const float* xg = x + (size_t)tBase * DD;

    float acc[4][4];
#pragma unroll
    for (int i = 0; i < 4; ++i)
#pragma unroll
        for (int j = 0; j < 4; ++j) acc[i][j] = 0.f;

    const int xswz = ty & 7;
    const int wswz = tx & 7;

    // ---- staging: 8 global_load_lds (16B) per wave per chunk, swizzled source ----
    auto stage = [&](int buf, int c) {
        const int k0 = c * BK;
#pragma unroll
        for (int i = 0; i < 4; ++i) {
            const int row = 16 * wv_id + 4 * i + rg;      // token row / expert row
            const int qc  = p ^ (row & 7);                // source quad (swizzle)
            const float* gx = xg + (size_t)row * DD + k0 + 4 * qc;
            const float* gw = W  + (size_t)row * DD + k0 + 4 * qc;
            __builtin_amdgcn_global_load_lds(
                (const __attribute__((address_space(1))) void*)gx,
                (__attribute__((address_space(3))) void*)&xs[buf][(16 * wv_id + 4 * i) * BK],
                16, 0, 0);
            __builtin_amdgcn_global_load_lds(
                (const __attribute__((address_space(1))) void*)gw,
                (__attribute__((address_space(3))) void*)&ws[buf][(16 * wv_id + 4 * i) * BK],
                16, 0, 0);
        }
    };

    // ---- compute one 64-k chunk ----
    auto compute = [&](int buf) {
#pragma unroll
        for (int k4 = 0; k4 < BK / 4; ++k4) {
            float4 xv[4], wv[4];
#pragma unroll
            for (int i = 0; i < 4; ++i)   // 4 distinct rows, distinct bank-quads: conflict-free
                xv[i] = *(const float4*)&xs[buf][(ty + 16 * i) * BK + 4 * (k4 ^ xswz)];
#pragma unroll
            for (int j = 0; j < 4; ++j)   // 16 rows over 8 bank-quads: 2-way, free
                wv[j] = *(const float4*)&ws[buf][(tx + 16 * j) * BK + 4 * (k4 ^ wswz)];
#pragma unroll
            for (int i = 0; i < 4; ++i)
#pragma unroll
                for (int j = 0; j < 4; ++j) {
                    acc[i][j] += xv[i].x * wv[j].x;
                    acc[i][j] += xv[i].y * wv[j].y;
                    acc[i][j] += xv[i].z * wv[j].z;
                    acc[i][j] += xv[i].w * wv[j].w;
                }
        }
    };

    // ---- double-buffered main loop; prefetch stays in flight across barriers ----
    stage(0, 0);
    int cur = 0;
#pragma unroll 1
    for (int c = 0; c < NCHUNK - 1; ++c) {
        stage(cur ^ 1, c + 1);
        // wait until only the 8 just-issued prefetch loads are outstanding -> cur buf ready
        asm volatile("s_waitcnt vmcnt(8)\n\ts_barrier" ::: "memory");
        compute(cur);
        // my ds_reads returned; all waves done reading -> next iter may overwrite
        asm volatile("s_waitcnt lgkmcnt(0)\n\ts_barrier" ::: "memory");
        cur ^= 1;
    }
    asm volatile("s_waitcnt vmcnt(0)\n\ts_barrier" ::: "memory");
    compute(cur);

    // ---- epilogue: logits -> LDS, top-2 + softmax ----
    float bvals[4];
#pragma unroll
    for (int j = 0; j < 4; ++j) bvals[j] = bias_g[tx + 16 * j];
#pragma unroll
    for (int i = 0; i < 4; ++i)
#pragma unroll
        for (int j = 0; j < 4; ++j)
            logits[(ty + 16 * i) * LSTR + (tx + 16 * j)] = acc[i][j] + bvals[j];
    __syncthreads();

    if (tid < TM) {
        const float* lrow = &logits[tid * LSTR];
        float v1 = -INFINITY, v2 = -INFINITY;
        int   i1 = 0, i2 = 0;
        for (int e = 0; e < EE; ++e) {
            const float v = lrow[e];
            if (v > v1) { v2 = v1; i2 = i1; v1 = v; i1 = e; }
            else if (v > v2) { v2 = v; i2 = e; }
        }
        const float ed  = expf(v2 - v1);
        const float inv = 1.f / (1.f + ed);
        const int tok = tBase + tid;
        out[tok * 2 + 0] = inv;
        out[tok * 2 + 1] = ed * inv;
        float* oidx = out + (size_t)2 * n_tokens;
        oidx[tok * 2 + 0] = (float)i1;
        oidx[tok * 2 + 1] = (float)i2;
    }
}

extern "C" void kernel_launch(void* const* d_in, const int* in_sizes, int n_in,
                              void* d_out, int out_size, void* d_ws, size_t ws_size,
                              hipStream_t stream) {
    const float* x = (const float*)d_in[0];
    const float* W = (const float*)d_in[1];
    const float* b = (const float*)d_in[2];
    float* out = (float*)d_out;

    const int n_tokens = in_sizes[0] / DD;  // 16384
    const int n_blocks = n_tokens / TM;     // 256

    router_kernel<<<n_blocks, THREADS, 0, stream>>>(x, W, b, out, n_tokens);
}